// Round 3
// baseline (443.500 us; speedup 1.0000x reference)
//
#include <hip/hip_runtime.h>

#define BB 32
#define HH 56
#define WW 56
#define CC 256
#define PSTRIP 4
#define STRIPS_PER_ROW (WW / PSTRIP)           // 14
#define STRIPS_PER_IMG (HH * STRIPS_PER_ROW)   // 784
#define BLOCKS_PER_IMG (STRIPS_PER_IMG * 32 / 256)  // 98

typedef float floatx4 __attribute__((ext_vector_type(4)));

__device__ __forceinline__ void load8(const float* __restrict__ p, float v[8]) {
    float4 a = *reinterpret_cast<const float4*>(p);
    float4 b = *reinterpret_cast<const float4*>(p + 4);
    v[0]=a.x; v[1]=a.y; v[2]=a.z; v[3]=a.w;
    v[4]=b.x; v[5]=b.y; v[6]=b.z; v[7]=b.w;
}

// thread = (group g of 8 channels, strip of PSTRIP pixels along W).
// lanes 0..31 = the 32 groups of one pixel -> contiguous 1KB coalesced rows.
//
// XCD-affinity swizzle: blocks dispatch round-robin to XCDs (blockIdx % 8).
// One image is 56*57KB = 3.2MB and fits a single XCD's 4MB L2, so we pin
// image b to XCD b%8 (4 images/XCD, streamed sequentially). All 9 stencil
// taps then hit L2 after first touch -> FETCH ~= x read once.
// Output stores are non-temporal so the 3.2MB of writes per image don't
// evict the L2-resident x tile.
__global__ __launch_bounds__(256, 4) void dn_kernel(
    const float* __restrict__ x,
    const float* __restrict__ gk_g,
    const float* __restrict__ gs_g,
    const float* __restrict__ beta,
    const float* __restrict__ beta_o,
    const float* __restrict__ gamma_o,
    const int* __restrict__ sdist,
    float* __restrict__ out)
{
    const int d    = sdist[0];                 // surround_dist (uniform scalar)
    const int xcd  = blockIdx.x & 7;
    const int slot = blockIdx.x >> 3;          // 0..391
    const int b    = xcd + ((slot / BLOCKS_PER_IMG) << 3);  // image 0..31
    const int ib   = slot % BLOCKS_PER_IMG;    // block within image, 0..97

    const int g     = threadIdx.x & 31;
    const int s_img = ib * 8 + (threadIdx.x >> 5);  // strip within image
    const int sw    = s_img % STRIPS_PER_ROW;
    const int h     = s_img / STRIPS_PER_ROW;
    const int w0    = sw * PSTRIP;
    const int c0    = g << 3;

    // gamma_k[0,0].reshape(8,G,8): w[i][g][o] = gk_g[i*CC + g*8 + o]
    float gk[8][8];
#pragma unroll
    for (int i = 0; i < 8; ++i) load8(gk_g + i*CC + c0, gk[i]);

    // gamma_s (3,3,C,1), center tap (1,1) masked out -> 8 taps
    const int tap_kh[8] = {0,0,0,1,1,2,2,2};
    const int tap_kw[8] = {0,1,2,0,2,0,1,2};
    float gs[8][8];
#pragma unroll
    for (int t = 0; t < 8; ++t)
        load8(gs_g + (tap_kh[t]*3 + tap_kw[t])*CC + c0, gs[t]);

    float betav[8], gov[8], bov[8];
    load8(beta    + c0, betav);
    load8(gamma_o + c0, gov);
    load8(beta_o  + c0, bov);
#pragma unroll
    for (int o = 0; o < 8; ++o) betav[o] += 1e-6f;   // BETA_MIN

    const float* xrow = x   + (size_t)((b*HH + h)*WW)*CC;
    float*       orow = out + (size_t)((b*HH + h)*WW)*CC;

#pragma unroll
    for (int j = 0; j < PSTRIP; ++j) {
        const int w = w0 + j;

        float cx[8];
        load8(xrow + w*CC + c0, cx);

        float acc[8];
#pragma unroll
        for (int o = 0; o < 8; ++o) acc[o] = betav[o];

        // Pk: 8x8 per-group mix of x^2
#pragma unroll
        for (int i = 0; i < 8; ++i) {
            const float x2 = cx[i]*cx[i];
#pragma unroll
            for (int o = 0; o < 8; ++o) acc[o] += x2 * gk[i][o];
        }

        // Ps: 8 masked depthwise taps on x^2 (dilation d, zero padding)
#pragma unroll
        for (int t = 0; t < 8; ++t) {
            const int hh = h + (tap_kh[t]-1)*d;
            const int w2 = w + (tap_kw[t]-1)*d;
            if (hh >= 0 && hh < HH && w2 >= 0 && w2 < WW) {
                float xn[8];
                load8(x + (size_t)((b*HH + hh)*WW + w2)*CC + c0, xn);
#pragma unroll
                for (int o = 0; o < 8; ++o) acc[o] += (xn[o]*xn[o]) * gs[t][o];
            }
        }

        floatx4 r0, r1;
        {
            float res[8];
#pragma unroll
            for (int o = 0; o < 8; ++o) {
                const float np = __builtin_amdgcn_rsqf(acc[o]);   // v_rsq_f32
                res[o] = cx[o] * np * gov[o] + bov[o];
            }
            r0 = (floatx4){res[0], res[1], res[2], res[3]};
            r1 = (floatx4){res[4], res[5], res[6], res[7]};
        }
        floatx4* op = reinterpret_cast<floatx4*>(orow + w*CC + c0);
        __builtin_nontemporal_store(r0, op);
        __builtin_nontemporal_store(r1, op + 1);
    }
}

extern "C" void kernel_launch(void* const* d_in, const int* in_sizes, int n_in,
                              void* d_out, int out_size, void* d_ws, size_t ws_size,
                              hipStream_t stream) {
    const float* x       = (const float*)d_in[0];
    const float* gamma_k = (const float*)d_in[1];
    const float* gamma_s = (const float*)d_in[2];
    const float* beta    = (const float*)d_in[3];
    const float* beta_o  = (const float*)d_in[4];
    const float* gamma_o = (const float*)d_in[5];
    const int*   sdist   = (const int*)d_in[6];
    float* out = (float*)d_out;

    // threads = B*H*(W/PSTRIP)*32 groups = 32*56*14*32 = 802816 -> 3136 blocks
    const int total  = BB * HH * STRIPS_PER_ROW * 32;
    const int blocks = total / 256;
    dn_kernel<<<blocks, 256, 0, stream>>>(x, gamma_k, gamma_s, beta,
                                          beta_o, gamma_o, sdist, out);
}

// Round 4
// 244.780 us; speedup vs baseline: 1.8118x; 1.8118x over previous
//
#include <hip/hip_runtime.h>

#define BB 32
#define HH 56
#define WW 56
#define CC 256
#define PSTRIP 4
#define STRIPS_PER_ROW (WW / PSTRIP)           // 14
#define STRIPS_PER_IMG (HH * STRIPS_PER_ROW)   // 784
#define BLOCKS_PER_IMG (STRIPS_PER_IMG * 32 / 256)  // 98

typedef float floatx4 __attribute__((ext_vector_type(4)));

__device__ __forceinline__ void load8(const float* __restrict__ p, float v[8]) {
    float4 a = *reinterpret_cast<const float4*>(p);
    float4 b = *reinterpret_cast<const float4*>(p + 4);
    v[0]=a.x; v[1]=a.y; v[2]=a.z; v[3]=a.w;
    v[4]=b.x; v[5]=b.y; v[6]=b.z; v[7]=b.w;
}

// thread = (group g of 8 channels, strip of PSTRIP pixels along W).
// lanes 0..31 = the 32 groups of one pixel -> contiguous 1KB coalesced rows.
//
// XCD-affinity swizzle: blocks dispatch round-robin to XCDs (blockIdx % 8).
// One image is 56*57KB = 3.2MB and fits a single XCD's 4MB L2, so we pin
// image b to XCD b%8 (4 images/XCD, streamed sequentially). All 9 stencil
// taps then hit L2 after first touch -> FETCH ~= x read once.
// Output stores are non-temporal so the 3.2MB of writes per image don't
// evict the L2-resident x tile.
//
// NOTE launch_bounds: (256,2) NOT (256,4). Live state is ~170 floats;
// (256,4) forced VGPR=64 -> scratch spills -> +286MB WRITE / +440MB FETCH
// of HBM spill traffic (R3 post-mortem). VGPR=112 with (256,2) is clean.
__global__ __launch_bounds__(256, 2) void dn_kernel(
    const float* __restrict__ x,
    const float* __restrict__ gk_g,
    const float* __restrict__ gs_g,
    const float* __restrict__ beta,
    const float* __restrict__ beta_o,
    const float* __restrict__ gamma_o,
    const int* __restrict__ sdist,
    float* __restrict__ out)
{
    const int d    = sdist[0];                 // surround_dist (uniform scalar)
    const int xcd  = blockIdx.x & 7;
    const int slot = blockIdx.x >> 3;          // 0..391
    const int b    = xcd + ((slot / BLOCKS_PER_IMG) << 3);  // image 0..31
    const int ib   = slot % BLOCKS_PER_IMG;    // block within image, 0..97

    const int g     = threadIdx.x & 31;
    const int s_img = ib * 8 + (threadIdx.x >> 5);  // strip within image
    const int sw    = s_img % STRIPS_PER_ROW;
    const int h     = s_img / STRIPS_PER_ROW;
    const int w0    = sw * PSTRIP;
    const int c0    = g << 3;

    // gamma_k[0,0].reshape(8,G,8): w[i][g][o] = gk_g[i*CC + g*8 + o]
    float gk[8][8];
#pragma unroll
    for (int i = 0; i < 8; ++i) load8(gk_g + i*CC + c0, gk[i]);

    // gamma_s (3,3,C,1), center tap (1,1) masked out -> 8 taps
    const int tap_kh[8] = {0,0,0,1,1,2,2,2};
    const int tap_kw[8] = {0,1,2,0,2,0,1,2};
    float gs[8][8];
#pragma unroll
    for (int t = 0; t < 8; ++t)
        load8(gs_g + (tap_kh[t]*3 + tap_kw[t])*CC + c0, gs[t]);

    float betav[8], gov[8], bov[8];
    load8(beta    + c0, betav);
    load8(gamma_o + c0, gov);
    load8(beta_o  + c0, bov);
#pragma unroll
    for (int o = 0; o < 8; ++o) betav[o] += 1e-6f;   // BETA_MIN

    const float* xrow = x   + (size_t)((b*HH + h)*WW)*CC;
    float*       orow = out + (size_t)((b*HH + h)*WW)*CC;

#pragma unroll
    for (int j = 0; j < PSTRIP; ++j) {
        const int w = w0 + j;

        float cx[8];
        load8(xrow + w*CC + c0, cx);

        float acc[8];
#pragma unroll
        for (int o = 0; o < 8; ++o) acc[o] = betav[o];

        // Pk: 8x8 per-group mix of x^2
#pragma unroll
        for (int i = 0; i < 8; ++i) {
            const float x2 = cx[i]*cx[i];
#pragma unroll
            for (int o = 0; o < 8; ++o) acc[o] += x2 * gk[i][o];
        }

        // Ps: 8 masked depthwise taps on x^2 (dilation d, zero padding)
#pragma unroll
        for (int t = 0; t < 8; ++t) {
            const int hh = h + (tap_kh[t]-1)*d;
            const int w2 = w + (tap_kw[t]-1)*d;
            if (hh >= 0 && hh < HH && w2 >= 0 && w2 < WW) {
                float xn[8];
                load8(x + (size_t)((b*HH + hh)*WW + w2)*CC + c0, xn);
#pragma unroll
                for (int o = 0; o < 8; ++o) acc[o] += (xn[o]*xn[o]) * gs[t][o];
            }
        }

        floatx4 r0, r1;
        {
            float res[8];
#pragma unroll
            for (int o = 0; o < 8; ++o) {
                const float np = __builtin_amdgcn_rsqf(acc[o]);   // v_rsq_f32
                res[o] = cx[o] * np * gov[o] + bov[o];
            }
            r0 = (floatx4){res[0], res[1], res[2], res[3]};
            r1 = (floatx4){res[4], res[5], res[6], res[7]};
        }
        floatx4* op = reinterpret_cast<floatx4*>(orow + w*CC + c0);
        __builtin_nontemporal_store(r0, op);
        __builtin_nontemporal_store(r1, op + 1);
    }
}

extern "C" void kernel_launch(void* const* d_in, const int* in_sizes, int n_in,
                              void* d_out, int out_size, void* d_ws, size_t ws_size,
                              hipStream_t stream) {
    const float* x       = (const float*)d_in[0];
    const float* gamma_k = (const float*)d_in[1];
    const float* gamma_s = (const float*)d_in[2];
    const float* beta    = (const float*)d_in[3];
    const float* beta_o  = (const float*)d_in[4];
    const float* gamma_o = (const float*)d_in[5];
    const int*   sdist   = (const int*)d_in[6];
    float* out = (float*)d_out;

    // threads = B*H*(W/PSTRIP)*32 groups = 32*56*14*32 = 802816 -> 3136 blocks
    const int total  = BB * HH * STRIPS_PER_ROW * 32;
    const int blocks = total / 256;
    dn_kernel<<<blocks, 256, 0, stream>>>(x, gamma_k, gamma_s, beta,
                                          beta_o, gamma_o, sdist, out);
}